// Round 13
// baseline (2463.855 us; speedup 1.0000x reference)
//
#include <hip/hip_runtime.h>
#include <hip/hip_fp16.h>
#include <stdint.h>

#define B_  64
#define T_  512
#define H1_ 257

typedef _Float16 h2v __attribute__((ext_vector_type(2)));

__device__ __forceinline__ float frcp(float x) { return __builtin_amdgcn_rcpf(x); }
__device__ __forceinline__ float frsq(float x) { return __builtin_amdgcn_rsqf(x); }
__device__ __forceinline__ h2v u2h(uint32_t u) { return __builtin_bit_cast(h2v, u); }
__device__ __forceinline__ float fdot2(uint32_t a, uint32_t b, float c) {
  return __builtin_amdgcn_fdot2(u2h(a), u2h(b), c, false);
}
__device__ __forceinline__ uint32_t pkh(float a, float b) {
  __half2 h = __halves2half2(__float2half(a), __float2half(b));
  return __builtin_bit_cast(uint32_t, h);
}

// raw barrier: orders LDS (lgkmcnt) but does NOT drain vmcnt.
#define LDS_BAR() do { \
  asm volatile("s_waitcnt lgkmcnt(0)" ::: "memory"); \
  __builtin_amdgcn_s_barrier(); \
  asm volatile("" ::: "memory"); \
} while (0)

// ---- DPP wave64 sum (6 steps + readlane63) ----
template <int CTRL>
__device__ __forceinline__ float dpp_add(float v) {
  int t = __builtin_amdgcn_update_dpp(0, __builtin_bit_cast(int, v), CTRL, 0xf, 0xf, true);
  return v + __builtin_bit_cast(float, t);
}
__device__ __forceinline__ float wsum(float v) {
  v = dpp_add<0xB1>(v);  v = dpp_add<0x4E>(v);
  v = dpp_add<0x141>(v); v = dpp_add<0x140>(v);
  v = dpp_add<0x142>(v); v = dpp_add<0x143>(v);
  return __builtin_bit_cast(float, __builtin_amdgcn_readlane(__builtin_bit_cast(int, v), 63));
}
// two INDEPENDENT wave sums, DPP chains interleaved => ~1 latency instead of 2
__device__ __forceinline__ void wsum2(float a, float b, float& ra, float& rb) {
  a = dpp_add<0xB1>(a);  b = dpp_add<0xB1>(b);
  a = dpp_add<0x4E>(a);  b = dpp_add<0x4E>(b);
  a = dpp_add<0x141>(a); b = dpp_add<0x141>(b);
  a = dpp_add<0x140>(a); b = dpp_add<0x140>(b);
  a = dpp_add<0x142>(a); b = dpp_add<0x142>(b);
  a = dpp_add<0x143>(a); b = dpp_add<0x143>(b);
  ra = __builtin_bit_cast(float, __builtin_amdgcn_readlane(__builtin_bit_cast(int, a), 63));
  rb = __builtin_bit_cast(float, __builtin_amdgcn_readlane(__builtin_bit_cast(int, b), 63));
}
__device__ __forceinline__ float sq4w(const float* s) {
  return wsum(s[0]*s[0] + s[1]*s[1] + s[2]*s[2] + s[3]*s[3]);
}
__device__ __forceinline__ float dot4w(const float* a, const float* b) {
  return wsum(a[0]*b[0] + a[1]*b[1] + a[2]*b[2] + a[3]*b[3]);
}

// logmap0 scale factor; ss must be TRUE |s|^2 (consistency-critical)
__device__ __forceinline__ float logc_(float x0, float ss, float sqrtK, float rsqK) {
  float yn = sqrtf(fmaxf(ss, 1e-30f));
  float th = fmaxf(x0 * rsqK, 1.0f + 1e-7f);
  float ac = __logf(th + sqrtf(th*th - 1.0f));
  return sqrtK * ac * frcp(yn);
}

// mobius-add BODY: xs' = (ch - sh*ciw)*xs + sh*lm. Caller supplies dotXL = xs·lm
// and computes the (exact) final norm itself — enables paired reductions.
__device__ __forceinline__ void madd_body(float* xs, float ss, float x0,
                                          const float* lm, float ssl, float dotXL,
                                          float K, float sqrtK, float rsqK) {
  float inv = frsq(fmaxf(ss, 1e-30f));
  float alpha = inv * dotXL * rsqK;
  float c2 = alpha * (sqrtK - x0);
  float ciw = c2 * inv;
  float ux = dotXL - ciw * ss;
  float w0 = ux * frcp(fmaxf(x0, 1e-7f));
  float ssw = fmaxf(ssl - 2.0f*ciw*dotXL + ciw*ciw*ss, 0.0f);
  float md = ssw - w0 * w0;
  float mn = sqrtf(fmaxf(md, 1e-7f));
  float th = fmaxf(fminf(mn, 1e6f) * rsqK, 1e-15f);
  float ex = __expf(th), ei = frcp(ex);
  float ch = 0.5f * (ex + ei);
  float sh = 0.5f * (ex - ei) * frcp(th);
  float A = ch - sh * ciw;
#pragma unroll
  for (int e = 0; e < 4; ++e) xs[e] = A * xs[e] + sh * lm[e];
}

// small-theta madds body (bias, |lm|~1e-4): algebraic nss carry (feed-forward safe)
__device__ __forceinline__ float madds_body(float* xs, float ss, float x0,
                                            const float* lm, float ssl, float dotXL,
                                            float sqrtK, float rsqK) {
  float inv = frsq(fmaxf(ss, 1e-30f));
  float alpha = inv * dotXL * rsqK;
  float c2 = alpha * (sqrtK - x0);
  float ciw = c2 * inv;
  float ux = dotXL - ciw * ss;
  float ssw = fmaxf(ssl - 2.0f*ciw*dotXL + ciw*ciw*ss, 0.0f);
  float nss = fmaxf(ss + 2.0f*ux + ssw, 0.0f);
  float Bc = 1.0f - ciw;
#pragma unroll
  for (int e = 0; e < 4; ++e) xs[e] = Bc * xs[e] + lm[e];
  return nss;
}

// gate: v (GEMV out, clobbered) ⊕-chain with lq(=xU) and bias; sigmoid out.
// 2 paired wsum slots (entry pair, post-maddc pair).
__device__ __forceinline__ void gate_chain(float* v, const float* lq, float ssl_q,
                                           const float* lmb, float ssl_b,
                                           float K, float sqrtK, float rsqK, float* sig) {
  float ssv, dvl;
  wsum2(v[0]*v[0]+v[1]*v[1]+v[2]*v[2]+v[3]*v[3],
        v[0]*lq[0]+v[1]*lq[1]+v[2]*lq[2]+v[3]*lq[3], ssv, dvl);
  // expmap0+proj (scale by ce); dotXL via reassociation ce*dvl (feed-forward)
  float sn = sqrtf(fmaxf(ssv, 1e-30f));
  float th = sn * rsqK;
  float ex = __expf(th), ei = frcp(ex);
  float sh = 0.5f * (ex - ei);
  float ce = sqrtK * sh * frcp(sn);
#pragma unroll
  for (int e = 0; e < 4; ++e) v[e] = ce * v[e];
  float tq = sqrtK * sh;
  float ss = tq * tq;
  float x0 = sqrtf(fmaxf(K + ss, 1e-7f));
  madd_body(v, ss, x0, lq, ssl_q, ce * dvl, K, sqrtK, rsqK);
  float ssm, dbm;
  wsum2(v[0]*v[0]+v[1]*v[1]+v[2]*v[2]+v[3]*v[3],
        v[0]*lmb[0]+v[1]*lmb[1]+v[2]*lmb[2]+v[3]*lmb[3], ssm, dbm);
  float x0m = sqrtf(fmaxf(K + ssm, 1e-7f));
  float nss = madds_body(v, ssm, x0m, lmb, ssl_b, dbm, sqrtK, rsqK);
  float x0f = sqrtf(fmaxf(K + nss, 1e-7f));
  float c = logc_(x0f, nss, sqrtK, rsqK);
#pragma unroll
  for (int e = 0; e < 4; ++e) sig[e] = frcp(1.0f + __expf(-c * v[e]));
}

// ---------------- pack weights: uint4[k4*768+col] = 4x half2 ----------------
__global__ void pack_weights(const float* __restrict__ wih, const float* __restrict__ whh,
                             uint4* __restrict__ Pih, uint4* __restrict__ Phh) {
  int idx = blockIdx.x * 256 + threadIdx.x;
  int m   = idx / 24576;
  int rem = idx % 24576;
  int k4  = rem / 768;
  int col = rem % 768;
  int g   = col >> 8;
  int j   = col & 255;
  int gsrc = (g == 0) ? 2 : ((g == 1) ? 0 : 1);
  const float* src = (m == 0) ? wih : whh;
  const float* row = src + (size_t)(gsrc * H1_ + 1 + j) * H1_ + 1 + 8 * k4;
  uint4 o;
  o.x = pkh(row[0], row[1]);
  o.y = pkh(row[2], row[3]);
  o.z = pkh(row[4], row[5]);
  o.w = pkh(row[6], row[7]);
  ((m == 0) ? Pih : Phh)[(size_t)k4 * 768 + col] = o;
}

// ---------------- precompute xU[t*64+b][768] = x_row @ U^T ----------------
__global__ void precompute_xu(const float* __restrict__ x, const uint4* __restrict__ U4,
                              float* __restrict__ xU) {
  __shared__ __align__(16) uint32_t xp[8][128];
  const int tid = threadIdx.x;
  const int row0 = blockIdx.x * 8;
#pragma unroll
  for (int it = 0; it < 4; ++it) {
    int item = it * 256 + tid;
    int r = item >> 7, i = item & 127;
    int row = row0 + r;
    int t = row >> 6, bb = row & 63;
    const float* xr = x + ((size_t)bb * T_ + t) * 256;
    float2 xv = ((const float2*)xr)[i];
    xp[r][i] = pkh(xv.x, xv.y);
  }
  __syncthreads();
  float acc[8][3];
#pragma unroll
  for (int r = 0; r < 8; ++r)
#pragma unroll
    for (int c = 0; c < 3; ++c) acc[r][c] = 0.f;

#pragma unroll 2
  for (int k4 = 0; k4 < 32; ++k4) {
    uint4 w0 = U4[(size_t)k4 * 768 + tid];
    uint4 w1 = U4[(size_t)k4 * 768 + 256 + tid];
    uint4 w2 = U4[(size_t)k4 * 768 + 512 + tid];
#pragma unroll
    for (int r = 0; r < 8; ++r) {
      uint4 gp = ((const uint4*)xp[r])[k4];
      acc[r][0] = fdot2(w0.x, gp.x, acc[r][0]); acc[r][0] = fdot2(w0.y, gp.y, acc[r][0]);
      acc[r][0] = fdot2(w0.z, gp.z, acc[r][0]); acc[r][0] = fdot2(w0.w, gp.w, acc[r][0]);
      acc[r][1] = fdot2(w1.x, gp.x, acc[r][1]); acc[r][1] = fdot2(w1.y, gp.y, acc[r][1]);
      acc[r][1] = fdot2(w1.z, gp.z, acc[r][1]); acc[r][1] = fdot2(w1.w, gp.w, acc[r][1]);
      acc[r][2] = fdot2(w2.x, gp.x, acc[r][2]); acc[r][2] = fdot2(w2.y, gp.y, acc[r][2]);
      acc[r][2] = fdot2(w2.z, gp.z, acc[r][2]); acc[r][2] = fdot2(w2.w, gp.w, acc[r][2]);
    }
  }
#pragma unroll
  for (int r = 0; r < 8; ++r)
#pragma unroll
    for (int c = 0; c < 3; ++c)
      xU[(size_t)(row0 + r) * 768 + c * 256 + tid] = acc[r][c];
}

// ---------------- xUss[row*3+g] = |xU_row_gate|^2 ----------------
__global__ void xuss_kernel(const float* __restrict__ xU, float* __restrict__ xUss) {
  int row  = (blockIdx.x * 256 + threadIdx.x) >> 6;
  int lane = threadIdx.x & 63;
  const float4* base = (const float4*)(xU + (size_t)row * 768);
#pragma unroll
  for (int g = 0; g < 3; ++g) {
    float4 v = base[g * 64 + lane];
    float s = wsum(v.x*v.x + v.y*v.y + v.z*v.z + v.w*v.w);
    if (lane == 63) xUss[(size_t)row * 3 + g] = s;
  }
}

// ---------------- sequential scan, one WG per batch row ----------------
// ALL weights (W_z, W_r, W_h) in registers (48 uint4/thread, split-K x2);
// gh computation folded into h-chain tail; paired wsum reductions on the spine.
__global__ __launch_bounds__(512, 1) void mobius_gru_scan(
    const float* __restrict__ xU, const float* __restrict__ xUss,
    const uint4* __restrict__ W4, const float* __restrict__ bias,
    const float* __restrict__ kin, float* __restrict__ out) {
  __shared__ __align__(16) uint32_t lds_gp[128];   // packed g vector (256 halves)
  __shared__ __align__(16) float lds_v[512];       // r-gate split-K partials
  __shared__ __align__(16) float lds_v2[512];      // z-gate split-K partials
  __shared__ __align__(16) float lds_vh[512];      // h-gate split-K partials
  __shared__ __align__(16) float lds_zg[256];      // z gate

  const int tid  = threadIdx.x;
  const int lane = tid & 63;
  const int wave = tid >> 6;
  const int b    = blockIdx.x;
  const int j    = tid & 255;    // output col within gate
  const int kh   = tid >> 8;     // split-K half

  const float kk    = kin[0];
  const float K     = 1.0f / kk;
  const float sqrtK = sqrtf(K);
  const float rsqK  = 1.0f / sqrtK;

  // ---- W_z, W_r, W_h: load once, pin into register file ----
  uint4 vz[16], vr[16], vh[16];
#pragma unroll
  for (int i = 0; i < 16; ++i) vz[i] = W4[(size_t)(kh * 16 + i) * 768 + j];
#pragma unroll
  for (int i = 0; i < 16; ++i) vr[i] = W4[(size_t)(kh * 16 + i) * 768 + 256 + j];
#pragma unroll
  for (int i = 0; i < 16; ++i) vh[i] = W4[(size_t)(kh * 16 + i) * 768 + 512 + j];
#pragma unroll
  for (int i = 0; i < 16; ++i) {
    asm volatile("" : "+v"(vz[i].x), "+v"(vz[i].y), "+v"(vz[i].z), "+v"(vz[i].w));
    asm volatile("" : "+v"(vr[i].x), "+v"(vr[i].y), "+v"(vr[i].z), "+v"(vr[i].w));
    asm volatile("" : "+v"(vh[i].x), "+v"(vh[i].y), "+v"(vh[i].z), "+v"(vh[i].w));
  }

  // bias tangent = spatial part; |b|^2 per gate (z,r,h <- rows 2,0,1)
  float lmeb[3][4]; float sslb[3];
  {
    const int rows[3] = {2, 0, 1};
#pragma unroll
    for (int g = 0; g < 3; ++g) {
#pragma unroll
      for (int e = 0; e < 4; ++e) lmeb[g][e] = bias[rows[g] * H1_ + 1 + 4 * lane + e];
      sslb[g] = sq4w(lmeb[g]);
    }
  }

  float h0c = 0.f, hs[4] = {0.f, 0.f, 0.f, 0.f}, ssh = 0.f;
  float gh[4] = {0.f, 0.f, 0.f, 0.f};   // logmap0(h), wave0-valid

  // per-wave xU slices (wave0: r,h; wave1: z), prefetched one step ahead
  float4 xvr_c = {0,0,0,0}, xvh_c = {0,0,0,0}, xvz_c = {0,0,0,0};
  float s0c = 0.f, s1c = 0.f, s2c = 0.f;
  if (wave == 0) {
    const float* xrow = xU + (size_t)b * 768;
    xvr_c = ((const float4*)(xrow + 256))[lane];
    xvh_c = ((const float4*)(xrow + 512))[lane];
    const float* srow = xUss + (size_t)b * 3;
    s1c = srow[1]; s2c = srow[2];
    // gh(t=0) = logmap0(zeros) = 0 -> packed zeros
    uint2 p; p.x = 0u; p.y = 0u;
    ((uint2*)lds_gp)[lane] = p;
  } else if (wave == 1) {
    const float* xrow = xU + (size_t)b * 768;
    xvz_c = ((const float4*)xrow)[lane];
    s0c = xUss[(size_t)b * 3];
  }

  __syncthreads();   // prologue gh + slices visible

  for (int t = 0; t < T_; ++t) {
    // (loop-top barrier = publish gh written by previous h-chain tail)
    if (t) LDS_BAR();   // B1

    // ---- phase1: r & z dots from registers (split-K x2); gp reads broadcast ----
    {
      float a0 = 0.f, a1 = 0.f, a2 = 0.f, a3 = 0.f;
      float c0 = 0.f, c1 = 0.f, c2 = 0.f, c3 = 0.f;
#pragma unroll
      for (int i = 0; i < 16; ++i) {
        uint4 gp = ((const uint4*)lds_gp)[kh * 16 + i];
        a0 = fdot2(vr[i].x, gp.x, a0);
        a1 = fdot2(vr[i].y, gp.y, a1);
        a2 = fdot2(vr[i].z, gp.z, a2);
        a3 = fdot2(vr[i].w, gp.w, a3);
        c0 = fdot2(vz[i].x, gp.x, c0);
        c1 = fdot2(vz[i].y, gp.y, c1);
        c2 = fdot2(vz[i].z, gp.z, c2);
        c3 = fdot2(vz[i].w, gp.w, c3);
      }
      lds_v[kh * 256 + j]  = (a0 + a1) + (a2 + a3);
      lds_v2[kh * 256 + j] = (c0 + c1) + (c2 + c3);
    }
    // prefetch next-step slices (waves 0/1 only; in flight across barriers)
    float4 xvr_n = {0,0,0,0}, xvh_n = {0,0,0,0}, xvz_n = {0,0,0,0};
    float s0n = 0.f, s1n = 0.f, s2n = 0.f;
    if (t + 1 < T_) {
      if (wave == 0) {
        const float* nx = xU + (size_t)((t + 1) * B_ + b) * 768;
        xvr_n = ((const float4*)(nx + 256))[lane];
        xvh_n = ((const float4*)(nx + 512))[lane];
        const float* srow = xUss + (size_t)((t + 1) * B_ + b) * 3;
        s1n = srow[1]; s2n = srow[2];
      } else if (wave == 1) {
        const float* nx = xU + (size_t)((t + 1) * B_ + b) * 768;
        xvz_n = ((const float4*)nx)[lane];
        s0n = xUss[(size_t)((t + 1) * B_ + b) * 3];
      }
    }
    LDS_BAR();   // B2

    if (wave == 0) {
      // ---- r-gate chain (SIMD0) ----
      float v[4], xv[4];
      {
        float4 pa = ((const float4*)lds_v)[lane];
        float4 pb = ((const float4*)lds_v)[64 + lane];
        v[0] = pa.x + pb.x; v[1] = pa.y + pb.y; v[2] = pa.z + pb.z; v[3] = pa.w + pb.w;
      }
      xv[0] = xvr_c.x; xv[1] = xvr_c.y; xv[2] = xvr_c.z; xv[3] = xvr_c.w;
      float rg[4];
      gate_chain(v, xv, s1c, lmeb[1], sslb[1], K, sqrtK, rsqK, rg);
      // lrh = logmap0(expmap0(r*gh)) == r*gh
      uint2 p;
      p.x = pkh(rg[0] * gh[0], rg[1] * gh[1]);
      p.y = pkh(rg[2] * gh[2], rg[3] * gh[3]);
      ((uint2*)lds_gp)[lane] = p;
    } else if (wave == 1) {
      // ---- z-gate chain (SIMD1, parallel) ----
      float v[4], xv[4];
      {
        float4 pa = ((const float4*)lds_v2)[lane];
        float4 pb = ((const float4*)lds_v2)[64 + lane];
        v[0] = pa.x + pb.x; v[1] = pa.y + pb.y; v[2] = pa.z + pb.z; v[3] = pa.w + pb.w;
      }
      xv[0] = xvz_c.x; xv[1] = xvz_c.y; xv[2] = xvz_c.z; xv[3] = xvz_c.w;
      float zg[4];
      gate_chain(v, xv, s0c, lmeb[0], sslb[0], K, sqrtK, rsqK, zg);
      float4 z4 = {zg[0], zg[1], zg[2], zg[3]};
      ((float4*)lds_zg)[lane] = z4;
    }
    LDS_BAR();   // B3

    // ---- phase3: GEMV-h from REGISTER weights; gp reads broadcast ----
    {
      float a0 = 0.f, a1 = 0.f, a2 = 0.f, a3 = 0.f;
#pragma unroll
      for (int i = 0; i < 16; ++i) {
        uint4 gp = ((const uint4*)lds_gp)[kh * 16 + i];
        a0 = fdot2(vh[i].x, gp.x, a0);
        a1 = fdot2(vh[i].y, gp.y, a1);
        a2 = fdot2(vh[i].z, gp.z, a2);
        a3 = fdot2(vh[i].w, gp.w, a3);
      }
      lds_vh[kh * 256 + j] = (a0 + a1) + (a2 + a3);
    }
    LDS_BAR();   // B4

    if (wave == 0) {
      // hoisted LDS reads (latency hidden under the chain head)
      float4 z4 = ((const float4*)lds_zg)[lane];
      float4 pa = ((const float4*)lds_vh)[lane];
      float4 pb = ((const float4*)lds_vh)[64 + lane];

      // ---- h_tilde chain ----
      float ts[4] = {pa.x + pb.x, pa.y + pb.y, pa.z + pb.z, pa.w + pb.w};
      float xv[4] = {xvh_c.x, xvh_c.y, xvh_c.z, xvh_c.w};
      float ssv, dvl;
      wsum2(ts[0]*ts[0]+ts[1]*ts[1]+ts[2]*ts[2]+ts[3]*ts[3],
            ts[0]*xv[0]+ts[1]*xv[1]+ts[2]*xv[2]+ts[3]*xv[3], ssv, dvl);
      float sn = sqrtf(fmaxf(ssv, 1e-30f));
      float th = sn * rsqK;
      float ex = __expf(th), ei = frcp(ex);
      float shh = 0.5f * (ex - ei);
      float ce = sqrtK * shh * frcp(sn);
#pragma unroll
      for (int e = 0; e < 4; ++e) ts[e] = ce * ts[e];
      float tq = sqrtK * shh;
      float sse = tq * tq;
      float x0e = sqrtf(fmaxf(K + sse, 1e-7f));
      madd_body(ts, sse, x0e, xv, s2c, ce * dvl, K, sqrtK, rsqK);
      float sst, dbm;
      wsum2(ts[0]*ts[0]+ts[1]*ts[1]+ts[2]*ts[2]+ts[3]*ts[3],
            ts[0]*lmeb[2][0]+ts[1]*lmeb[2][1]+ts[2]*lmeb[2][2]+ts[3]*lmeb[2][3],
            sst, dbm);
      float x0t = sqrtf(fmaxf(K + sst, 1e-7f));
      float nst = madds_body(ts, sst, x0t, lmeb[2], sslb[2], dbm, sqrtK, rsqK);
      float t0 = sqrtf(fmaxf(K + nst, 1e-7f));

      // lt = logmap0(h_tilde)[1:], sslt = K*acosh^2 (exact given nst carry, as R12)
      float ynt = sqrtf(fmaxf(nst, 1e-30f));
      float tht = fmaxf(t0 * rsqK, 1.0f + 1e-7f);
      float act = __logf(tht + sqrtf(tht*tht - 1.0f));
      float clt = sqrtK * act * frcp(ynt);
      float lt[4];
#pragma unroll
      for (int e = 0; e < 4; ++e) lt[e] = clt * ts[e];
      float sslt = K * act * act;

      // ---- delta_h = mobius_add(proj(-hx), h_tilde) ----
      float ns[4] = {-hs[0], -hs[1], -hs[2], -hs[3]};
      float n0 = sqrtf(fmaxf(K + ssh, 1e-7f));
      float dnl = dot4w(ns, lt);
      madd_body(ns, ssh, n0, lt, sslt, dnl, K, sqrtK, rsqK);
      float ssn2 = sq4w(ns);                      // exact
      float n02 = sqrtf(fmaxf(K + ssn2, 1e-7f));
      float cl2 = logc_(n02, ssn2, sqrtK, rsqK);  // ld = cl2*ns

      // ---- h_new = expmap(ptransp0(hx, z*ld), hx) ----
      float uu[4];
      uu[0] = z4.x * (cl2 * ns[0]); uu[1] = z4.y * (cl2 * ns[1]);
      uu[2] = z4.z * (cl2 * ns[2]); uu[3] = z4.w * (cl2 * ns[3]);
      float ssuu, dhu;
      wsum2(uu[0]*uu[0]+uu[1]*uu[1]+uu[2]*uu[2]+uu[3]*uu[3],
            hs[0]*uu[0]+hs[1]*uu[1]+hs[2]*uu[2]+hs[3]*uu[3], ssuu, dhu);
      madd_body(hs, ssh, h0c, uu, ssuu, dhu, K, sqrtK, rsqK);
      ssh = sq4w(hs);                             // EXACT (feedback state)
      h0c = sqrtf(fmaxf(K + ssh, 1e-7f));

      // ---- gh for next step (folded; reuses exact ssh) + publish + store ----
      float cg = logc_(h0c, ssh, sqrtK, rsqK);
#pragma unroll
      for (int e = 0; e < 4; ++e) gh[e] = cg * hs[e];
      uint2 p; p.x = pkh(gh[0], gh[1]); p.y = pkh(gh[2], gh[3]);
      ((uint2*)lds_gp)[lane] = p;

      float* orow = out + (size_t)(t * B_ + b) * H1_;
      if (lane == 0) orow[0] = h0c;
#pragma unroll
      for (int e = 0; e < 4; ++e) orow[1 + 4 * lane + e] = hs[e];
    }

    // rotate prefetched slices
    xvr_c = xvr_n; xvh_c = xvh_n; xvz_c = xvz_n;
    s0c = s0n; s1c = s1n; s2c = s2n;
  }

  if (wave == 0) {
    float4 hv = {hs[0], hs[1], hs[2], hs[3]};
    ((float4*)(out + (size_t)T_ * B_ * H1_ + (size_t)b * 256))[lane] = hv;
  }
}

// ---------------- launch ----------------
extern "C" void kernel_launch(void* const* d_in, const int* in_sizes, int n_in,
                              void* d_out, int out_size, void* d_ws, size_t ws_size,
                              hipStream_t stream) {
  const float* x    = (const float*)d_in[0];
  const float* k    = (const float*)d_in[1];
  const float* wih  = (const float*)d_in[2];
  const float* whh  = (const float*)d_in[3];
  const float* bias = (const float*)d_in[4];
  float* out = (float*)d_out;

  // ws: Pih (24576 uint4, overlaid by xUss) | Phh (24576 uint4) | xU (32768*768 f)
  uint4* Pih = (uint4*)d_ws;
  uint4* Phh = Pih + 24576;
  float* xU  = (float*)(Phh + 24576);
  float* xUss = (float*)Pih;   // Pih dead after precompute_xu

  pack_weights<<<192, 256, 0, stream>>>(wih, whh, Pih, Phh);
  precompute_xu<<<4096, 256, 0, stream>>>(x, Pih, xU);
  xuss_kernel<<<8192, 256, 0, stream>>>(xU, xUss);
  mobius_gru_scan<<<B_, 512, 0, stream>>>(xU, xUss, Phh, bias, k, out);
}

// Round 14
// 1950.130 us; speedup vs baseline: 1.2634x; 1.2634x over previous
//
#include <hip/hip_runtime.h>
#include <hip/hip_fp16.h>
#include <stdint.h>

#define B_  64
#define T_  512
#define H1_ 257

typedef _Float16 h2v __attribute__((ext_vector_type(2)));

__device__ __forceinline__ float frcp(float x) { return __builtin_amdgcn_rcpf(x); }
__device__ __forceinline__ float frsq(float x) { return __builtin_amdgcn_rsqf(x); }
__device__ __forceinline__ h2v u2h(uint32_t u) { return __builtin_bit_cast(h2v, u); }
__device__ __forceinline__ float fdot2(uint32_t a, uint32_t b, float c) {
  return __builtin_amdgcn_fdot2(u2h(a), u2h(b), c, false);
}
__device__ __forceinline__ uint32_t pkh(float a, float b) {
  __half2 h = __halves2half2(__float2half(a), __float2half(b));
  return __builtin_bit_cast(uint32_t, h);
}

// raw barrier: orders LDS (lgkmcnt) but does NOT drain vmcnt.
#define LDS_BAR() do { \
  asm volatile("s_waitcnt lgkmcnt(0)" ::: "memory"); \
  __builtin_amdgcn_s_barrier(); \
  asm volatile("" ::: "memory"); \
} while (0)

// ---- DPP wave64 sum (6 steps + readlane63) ----
template <int CTRL>
__device__ __forceinline__ float dpp_add(float v) {
  int t = __builtin_amdgcn_update_dpp(0, __builtin_bit_cast(int, v), CTRL, 0xf, 0xf, true);
  return v + __builtin_bit_cast(float, t);
}
__device__ __forceinline__ float wsum(float v) {
  v = dpp_add<0xB1>(v);  v = dpp_add<0x4E>(v);
  v = dpp_add<0x141>(v); v = dpp_add<0x140>(v);
  v = dpp_add<0x142>(v); v = dpp_add<0x143>(v);
  return __builtin_bit_cast(float, __builtin_amdgcn_readlane(__builtin_bit_cast(int, v), 63));
}
// two INDEPENDENT wave sums, DPP chains interleaved => ~1 latency instead of 2
__device__ __forceinline__ void wsum2(float a, float b, float& ra, float& rb) {
  a = dpp_add<0xB1>(a);  b = dpp_add<0xB1>(b);
  a = dpp_add<0x4E>(a);  b = dpp_add<0x4E>(b);
  a = dpp_add<0x141>(a); b = dpp_add<0x141>(b);
  a = dpp_add<0x140>(a); b = dpp_add<0x140>(b);
  a = dpp_add<0x142>(a); b = dpp_add<0x142>(b);
  a = dpp_add<0x143>(a); b = dpp_add<0x143>(b);
  ra = __builtin_bit_cast(float, __builtin_amdgcn_readlane(__builtin_bit_cast(int, a), 63));
  rb = __builtin_bit_cast(float, __builtin_amdgcn_readlane(__builtin_bit_cast(int, b), 63));
}
__device__ __forceinline__ float sq4w(const float* s) {
  return wsum(s[0]*s[0] + s[1]*s[1] + s[2]*s[2] + s[3]*s[3]);
}
__device__ __forceinline__ float dot4w(const float* a, const float* b) {
  return wsum(a[0]*b[0] + a[1]*b[1] + a[2]*b[2] + a[3]*b[3]);
}

// logmap0 scale factor; ss must be TRUE |s|^2 (consistency-critical)
__device__ __forceinline__ float logc_(float x0, float ss, float sqrtK, float rsqK) {
  float yn = sqrtf(fmaxf(ss, 1e-30f));
  float th = fmaxf(x0 * rsqK, 1.0f + 1e-7f);
  float ac = __logf(th + sqrtf(th*th - 1.0f));
  return sqrtK * ac * frcp(yn);
}

// mobius-add BODY: xs' = (ch - sh*ciw)*xs + sh*lm. Caller supplies dotXL = xs·lm
// and computes the (exact) final norm itself — enables paired reductions.
__device__ __forceinline__ void madd_body(float* xs, float ss, float x0,
                                          const float* lm, float ssl, float dotXL,
                                          float K, float sqrtK, float rsqK) {
  float inv = frsq(fmaxf(ss, 1e-30f));
  float alpha = inv * dotXL * rsqK;
  float c2 = alpha * (sqrtK - x0);
  float ciw = c2 * inv;
  float ux = dotXL - ciw * ss;
  float w0 = ux * frcp(fmaxf(x0, 1e-7f));
  float ssw = fmaxf(ssl - 2.0f*ciw*dotXL + ciw*ciw*ss, 0.0f);
  float md = ssw - w0 * w0;
  float mn = sqrtf(fmaxf(md, 1e-7f));
  float th = fmaxf(fminf(mn, 1e6f) * rsqK, 1e-15f);
  float ex = __expf(th), ei = frcp(ex);
  float ch = 0.5f * (ex + ei);
  float sh = 0.5f * (ex - ei) * frcp(th);
  float A = ch - sh * ciw;
#pragma unroll
  for (int e = 0; e < 4; ++e) xs[e] = A * xs[e] + sh * lm[e];
}

// small-theta madds body (bias, |lm|~1e-4): algebraic nss carry (feed-forward safe)
__device__ __forceinline__ float madds_body(float* xs, float ss, float x0,
                                            const float* lm, float ssl, float dotXL,
                                            float sqrtK, float rsqK) {
  float inv = frsq(fmaxf(ss, 1e-30f));
  float alpha = inv * dotXL * rsqK;
  float c2 = alpha * (sqrtK - x0);
  float ciw = c2 * inv;
  float ux = dotXL - ciw * ss;
  float ssw = fmaxf(ssl - 2.0f*ciw*dotXL + ciw*ciw*ss, 0.0f);
  float nss = fmaxf(ss + 2.0f*ux + ssw, 0.0f);
  float Bc = 1.0f - ciw;
#pragma unroll
  for (int e = 0; e < 4; ++e) xs[e] = Bc * xs[e] + lm[e];
  return nss;
}

// gate: v (GEMV out, clobbered) ⊕-chain with lq(=xU) and bias; sigmoid out.
__device__ __forceinline__ void gate_chain(float* v, const float* lq, float ssl_q,
                                           const float* lmb, float ssl_b,
                                           float K, float sqrtK, float rsqK, float* sig) {
  float ssv, dvl;
  wsum2(v[0]*v[0]+v[1]*v[1]+v[2]*v[2]+v[3]*v[3],
        v[0]*lq[0]+v[1]*lq[1]+v[2]*lq[2]+v[3]*lq[3], ssv, dvl);
  float sn = sqrtf(fmaxf(ssv, 1e-30f));
  float th = sn * rsqK;
  float ex = __expf(th), ei = frcp(ex);
  float sh = 0.5f * (ex - ei);
  float ce = sqrtK * sh * frcp(sn);
#pragma unroll
  for (int e = 0; e < 4; ++e) v[e] = ce * v[e];
  float tq = sqrtK * sh;
  float ss = tq * tq;
  float x0 = sqrtf(fmaxf(K + ss, 1e-7f));
  madd_body(v, ss, x0, lq, ssl_q, ce * dvl, K, sqrtK, rsqK);
  float ssm, dbm;
  wsum2(v[0]*v[0]+v[1]*v[1]+v[2]*v[2]+v[3]*v[3],
        v[0]*lmb[0]+v[1]*lmb[1]+v[2]*lmb[2]+v[3]*lmb[3], ssm, dbm);
  float x0m = sqrtf(fmaxf(K + ssm, 1e-7f));
  float nss = madds_body(v, ssm, x0m, lmb, ssl_b, dbm, sqrtK, rsqK);
  float x0f = sqrtf(fmaxf(K + nss, 1e-7f));
  float c = logc_(x0f, nss, sqrtK, rsqK);
#pragma unroll
  for (int e = 0; e < 4; ++e) sig[e] = frcp(1.0f + __expf(-c * v[e]));
}

// ---------------- pack weights: uint4[k4*768+col] = 4x half2 ----------------
__global__ void pack_weights(const float* __restrict__ wih, const float* __restrict__ whh,
                             uint4* __restrict__ Pih, uint4* __restrict__ Phh) {
  int idx = blockIdx.x * 256 + threadIdx.x;
  int m   = idx / 24576;
  int rem = idx % 24576;
  int k4  = rem / 768;
  int col = rem % 768;
  int g   = col >> 8;
  int j   = col & 255;
  int gsrc = (g == 0) ? 2 : ((g == 1) ? 0 : 1);
  const float* src = (m == 0) ? wih : whh;
  const float* row = src + (size_t)(gsrc * H1_ + 1 + j) * H1_ + 1 + 8 * k4;
  uint4 o;
  o.x = pkh(row[0], row[1]);
  o.y = pkh(row[2], row[3]);
  o.z = pkh(row[4], row[5]);
  o.w = pkh(row[6], row[7]);
  ((m == 0) ? Pih : Phh)[(size_t)k4 * 768 + col] = o;
}

// ---------------- precompute xU[t*64+b][768] = x_row @ U^T ----------------
__global__ void precompute_xu(const float* __restrict__ x, const uint4* __restrict__ U4,
                              float* __restrict__ xU) {
  __shared__ __align__(16) uint32_t xp[8][128];
  const int tid = threadIdx.x;
  const int row0 = blockIdx.x * 8;
#pragma unroll
  for (int it = 0; it < 4; ++it) {
    int item = it * 256 + tid;
    int r = item >> 7, i = item & 127;
    int row = row0 + r;
    int t = row >> 6, bb = row & 63;
    const float* xr = x + ((size_t)bb * T_ + t) * 256;
    float2 xv = ((const float2*)xr)[i];
    xp[r][i] = pkh(xv.x, xv.y);
  }
  __syncthreads();
  float acc[8][3];
#pragma unroll
  for (int r = 0; r < 8; ++r)
#pragma unroll
    for (int c = 0; c < 3; ++c) acc[r][c] = 0.f;

#pragma unroll 2
  for (int k4 = 0; k4 < 32; ++k4) {
    uint4 w0 = U4[(size_t)k4 * 768 + tid];
    uint4 w1 = U4[(size_t)k4 * 768 + 256 + tid];
    uint4 w2 = U4[(size_t)k4 * 768 + 512 + tid];
#pragma unroll
    for (int r = 0; r < 8; ++r) {
      uint4 gp = ((const uint4*)xp[r])[k4];
      acc[r][0] = fdot2(w0.x, gp.x, acc[r][0]); acc[r][0] = fdot2(w0.y, gp.y, acc[r][0]);
      acc[r][0] = fdot2(w0.z, gp.z, acc[r][0]); acc[r][0] = fdot2(w0.w, gp.w, acc[r][0]);
      acc[r][1] = fdot2(w1.x, gp.x, acc[r][1]); acc[r][1] = fdot2(w1.y, gp.y, acc[r][1]);
      acc[r][1] = fdot2(w1.z, gp.z, acc[r][1]); acc[r][1] = fdot2(w1.w, gp.w, acc[r][1]);
      acc[r][2] = fdot2(w2.x, gp.x, acc[r][2]); acc[r][2] = fdot2(w2.y, gp.y, acc[r][2]);
      acc[r][2] = fdot2(w2.z, gp.z, acc[r][2]); acc[r][2] = fdot2(w2.w, gp.w, acc[r][2]);
    }
  }
#pragma unroll
  for (int r = 0; r < 8; ++r)
#pragma unroll
    for (int c = 0; c < 3; ++c)
      xU[(size_t)(row0 + r) * 768 + c * 256 + tid] = acc[r][c];
}

// ---------------- xUss[row*3+g] = |xU_row_gate|^2 ----------------
__global__ void xuss_kernel(const float* __restrict__ xU, float* __restrict__ xUss) {
  int row  = (blockIdx.x * 256 + threadIdx.x) >> 6;
  int lane = threadIdx.x & 63;
  const float4* base = (const float4*)(xU + (size_t)row * 768);
#pragma unroll
  for (int g = 0; g < 3; ++g) {
    float4 v = base[g * 64 + lane];
    float s = wsum(v.x*v.x + v.y*v.y + v.z*v.z + v.w*v.w);
    if (lane == 63) xUss[(size_t)row * 3 + g] = s;
  }
}

// ---------------- sequential scan, one WG per batch row ----------------
// W_z+W_r pinned in registers (128 regs, fits); W_h in LDS (R13 spill lesson);
// paired wsum2 reductions; gh folded into h-chain tail; hoisted LDS reads.
__global__ __launch_bounds__(512, 1) void mobius_gru_scan(
    const float* __restrict__ xU, const float* __restrict__ xUss,
    const uint4* __restrict__ W4, const float* __restrict__ bias,
    const float* __restrict__ kin, float* __restrict__ out) {
  __shared__ __align__(16) uint4 LWH[32][256];     // 128 KB: h-gate weights
  __shared__ __align__(16) uint32_t lds_gp[128];   // packed g vector (256 halves)
  __shared__ __align__(16) float lds_v[512];       // r-gate split-K partials
  __shared__ __align__(16) float lds_v2[512];      // z-gate split-K partials
  __shared__ __align__(16) float lds_vh[512];      // h-gate split-K partials
  __shared__ __align__(16) float lds_zg[256];      // z gate

  const int tid  = threadIdx.x;
  const int lane = tid & 63;
  const int wave = tid >> 6;
  const int b    = blockIdx.x;
  const int j    = tid & 255;    // output col within gate
  const int kh   = tid >> 8;     // split-K half

  const float kk    = kin[0];
  const float K     = 1.0f / kk;
  const float sqrtK = sqrtf(K);
  const float rsqK  = 1.0f / sqrtK;

  // ---- stage W_h into LDS ----
#pragma unroll
  for (int it = 0; it < 16; ++it) {
    int idx = it * 512 + tid;
    int k4 = idx >> 8, jj = idx & 255;
    LWH[k4][jj] = W4[(size_t)k4 * 768 + 512 + jj];
  }

  // ---- W_z, W_r: load once, pin into register file ----
  uint4 vz[16], vr[16];
#pragma unroll
  for (int i = 0; i < 16; ++i) vz[i] = W4[(size_t)(kh * 16 + i) * 768 + j];
#pragma unroll
  for (int i = 0; i < 16; ++i) vr[i] = W4[(size_t)(kh * 16 + i) * 768 + 256 + j];
#pragma unroll
  for (int i = 0; i < 16; ++i) {
    asm volatile("" : "+v"(vz[i].x), "+v"(vz[i].y), "+v"(vz[i].z), "+v"(vz[i].w));
    asm volatile("" : "+v"(vr[i].x), "+v"(vr[i].y), "+v"(vr[i].z), "+v"(vr[i].w));
  }

  // bias tangent = spatial part; |b|^2 per gate (z,r,h <- rows 2,0,1)
  float lmeb[3][4]; float sslb[3];
  {
    const int rows[3] = {2, 0, 1};
#pragma unroll
    for (int g = 0; g < 3; ++g) {
#pragma unroll
      for (int e = 0; e < 4; ++e) lmeb[g][e] = bias[rows[g] * H1_ + 1 + 4 * lane + e];
      sslb[g] = sq4w(lmeb[g]);
    }
  }

  float h0c = 0.f, hs[4] = {0.f, 0.f, 0.f, 0.f}, ssh = 0.f;
  float gh[4] = {0.f, 0.f, 0.f, 0.f};   // logmap0(h), wave0-valid

  // per-wave xU slices (wave0: r,h; wave1: z), prefetched one step ahead
  float4 xvr_c = {0,0,0,0}, xvh_c = {0,0,0,0}, xvz_c = {0,0,0,0};
  float s0c = 0.f, s1c = 0.f, s2c = 0.f;
  if (wave == 0) {
    const float* xrow = xU + (size_t)b * 768;
    xvr_c = ((const float4*)(xrow + 256))[lane];
    xvh_c = ((const float4*)(xrow + 512))[lane];
    const float* srow = xUss + (size_t)b * 3;
    s1c = srow[1]; s2c = srow[2];
    // gh(t=0) = logmap0(zeros) = 0 -> packed zeros
    uint2 p; p.x = 0u; p.y = 0u;
    ((uint2*)lds_gp)[lane] = p;
  } else if (wave == 1) {
    const float* xrow = xU + (size_t)b * 768;
    xvz_c = ((const float4*)xrow)[lane];
    s0c = xUss[(size_t)b * 3];
  }

  __syncthreads();   // staging + prologue gh visible

  for (int t = 0; t < T_; ++t) {
    if (t) LDS_BAR();   // B1: publish gh from previous h-chain tail

    // ---- phase1: r & z dots from registers (split-K x2) ----
    {
      float a0 = 0.f, a1 = 0.f, a2 = 0.f, a3 = 0.f;
      float c0 = 0.f, c1 = 0.f, c2 = 0.f, c3 = 0.f;
#pragma unroll
      for (int i = 0; i < 16; ++i) {
        uint4 gp = ((const uint4*)lds_gp)[kh * 16 + i];
        a0 = fdot2(vr[i].x, gp.x, a0);
        a1 = fdot2(vr[i].y, gp.y, a1);
        a2 = fdot2(vr[i].z, gp.z, a2);
        a3 = fdot2(vr[i].w, gp.w, a3);
        c0 = fdot2(vz[i].x, gp.x, c0);
        c1 = fdot2(vz[i].y, gp.y, c1);
        c2 = fdot2(vz[i].z, gp.z, c2);
        c3 = fdot2(vz[i].w, gp.w, c3);
      }
      lds_v[kh * 256 + j]  = (a0 + a1) + (a2 + a3);
      lds_v2[kh * 256 + j] = (c0 + c1) + (c2 + c3);
    }
    // prefetch next-step slices (waves 0/1 only; in flight across barriers)
    float4 xvr_n = {0,0,0,0}, xvh_n = {0,0,0,0}, xvz_n = {0,0,0,0};
    float s0n = 0.f, s1n = 0.f, s2n = 0.f;
    if (t + 1 < T_) {
      if (wave == 0) {
        const float* nx = xU + (size_t)((t + 1) * B_ + b) * 768;
        xvr_n = ((const float4*)(nx + 256))[lane];
        xvh_n = ((const float4*)(nx + 512))[lane];
        const float* srow = xUss + (size_t)((t + 1) * B_ + b) * 3;
        s1n = srow[1]; s2n = srow[2];
      } else if (wave == 1) {
        const float* nx = xU + (size_t)((t + 1) * B_ + b) * 768;
        xvz_n = ((const float4*)nx)[lane];
        s0n = xUss[(size_t)((t + 1) * B_ + b) * 3];
      }
    }
    LDS_BAR();   // B2

    if (wave == 0) {
      // ---- r-gate chain (SIMD0) ----
      float v[4], xv[4];
      {
        float4 pa = ((const float4*)lds_v)[lane];
        float4 pb = ((const float4*)lds_v)[64 + lane];
        v[0] = pa.x + pb.x; v[1] = pa.y + pb.y; v[2] = pa.z + pb.z; v[3] = pa.w + pb.w;
      }
      xv[0] = xvr_c.x; xv[1] = xvr_c.y; xv[2] = xvr_c.z; xv[3] = xvr_c.w;
      float rg[4];
      gate_chain(v, xv, s1c, lmeb[1], sslb[1], K, sqrtK, rsqK, rg);
      // lrh = logmap0(expmap0(r*gh)) == r*gh
      uint2 p;
      p.x = pkh(rg[0] * gh[0], rg[1] * gh[1]);
      p.y = pkh(rg[2] * gh[2], rg[3] * gh[3]);
      ((uint2*)lds_gp)[lane] = p;
    } else if (wave == 1) {
      // ---- z-gate chain (SIMD1, parallel) ----
      float v[4], xv[4];
      {
        float4 pa = ((const float4*)lds_v2)[lane];
        float4 pb = ((const float4*)lds_v2)[64 + lane];
        v[0] = pa.x + pb.x; v[1] = pa.y + pb.y; v[2] = pa.z + pb.z; v[3] = pa.w + pb.w;
      }
      xv[0] = xvz_c.x; xv[1] = xvz_c.y; xv[2] = xvz_c.z; xv[3] = xvz_c.w;
      float zg[4];
      gate_chain(v, xv, s0c, lmeb[0], sslb[0], K, sqrtK, rsqK, zg);
      float4 z4 = {zg[0], zg[1], zg[2], zg[3]};
      ((float4*)lds_zg)[lane] = z4;
    }
    LDS_BAR();   // B3

    // ---- phase3: GEMV-h from LDS weights, split-K x2 ----
    {
      const uint4* wl = &LWH[kh * 16][j];
      float a0 = 0.f, a1 = 0.f, a2 = 0.f, a3 = 0.f;
#pragma unroll
      for (int i = 0; i < 16; ++i) {
        uint4 w  = wl[(size_t)i * 256];
        uint4 gp = ((const uint4*)lds_gp)[kh * 16 + i];
        a0 = fdot2(w.x, gp.x, a0);
        a1 = fdot2(w.y, gp.y, a1);
        a2 = fdot2(w.z, gp.z, a2);
        a3 = fdot2(w.w, gp.w, a3);
      }
      lds_vh[kh * 256 + j] = (a0 + a1) + (a2 + a3);
    }
    LDS_BAR();   // B4

    if (wave == 0) {
      // hoisted LDS reads (latency hidden under the chain head)
      float4 z4 = ((const float4*)lds_zg)[lane];
      float4 pa = ((const float4*)lds_vh)[lane];
      float4 pb = ((const float4*)lds_vh)[64 + lane];

      // ---- h_tilde chain ----
      float ts[4] = {pa.x + pb.x, pa.y + pb.y, pa.z + pb.z, pa.w + pb.w};
      float xv[4] = {xvh_c.x, xvh_c.y, xvh_c.z, xvh_c.w};
      float ssv, dvl;
      wsum2(ts[0]*ts[0]+ts[1]*ts[1]+ts[2]*ts[2]+ts[3]*ts[3],
            ts[0]*xv[0]+ts[1]*xv[1]+ts[2]*xv[2]+ts[3]*xv[3], ssv, dvl);
      float sn = sqrtf(fmaxf(ssv, 1e-30f));
      float th = sn * rsqK;
      float ex = __expf(th), ei = frcp(ex);
      float shh = 0.5f * (ex - ei);
      float ce = sqrtK * shh * frcp(sn);
#pragma unroll
      for (int e = 0; e < 4; ++e) ts[e] = ce * ts[e];
      float tq = sqrtK * shh;
      float sse = tq * tq;
      float x0e = sqrtf(fmaxf(K + sse, 1e-7f));
      madd_body(ts, sse, x0e, xv, s2c, ce * dvl, K, sqrtK, rsqK);
      float sst, dbm;
      wsum2(ts[0]*ts[0]+ts[1]*ts[1]+ts[2]*ts[2]+ts[3]*ts[3],
            ts[0]*lmeb[2][0]+ts[1]*lmeb[2][1]+ts[2]*lmeb[2][2]+ts[3]*lmeb[2][3],
            sst, dbm);
      float x0t = sqrtf(fmaxf(K + sst, 1e-7f));
      float nst = madds_body(ts, sst, x0t, lmeb[2], sslb[2], dbm, sqrtK, rsqK);
      float t0 = sqrtf(fmaxf(K + nst, 1e-7f));

      // lt = logmap0(h_tilde)[1:], sslt = K*acosh^2 (exact given nst carry)
      float ynt = sqrtf(fmaxf(nst, 1e-30f));
      float tht = fmaxf(t0 * rsqK, 1.0f + 1e-7f);
      float act = __logf(tht + sqrtf(tht*tht - 1.0f));
      float clt = sqrtK * act * frcp(ynt);
      float lt[4];
#pragma unroll
      for (int e = 0; e < 4; ++e) lt[e] = clt * ts[e];
      float sslt = K * act * act;

      // ---- delta_h = mobius_add(proj(-hx), h_tilde) ----
      float ns[4] = {-hs[0], -hs[1], -hs[2], -hs[3]};
      float n0 = sqrtf(fmaxf(K + ssh, 1e-7f));
      float dnl = dot4w(ns, lt);
      madd_body(ns, ssh, n0, lt, sslt, dnl, K, sqrtK, rsqK);
      float ssn2 = sq4w(ns);                      // exact
      float n02 = sqrtf(fmaxf(K + ssn2, 1e-7f));
      float cl2 = logc_(n02, ssn2, sqrtK, rsqK);  // ld = cl2*ns

      // ---- h_new = expmap(ptransp0(hx, z*ld), hx) ----
      float uu[4];
      uu[0] = z4.x * (cl2 * ns[0]); uu[1] = z4.y * (cl2 * ns[1]);
      uu[2] = z4.z * (cl2 * ns[2]); uu[3] = z4.w * (cl2 * ns[3]);
      float ssuu, dhu;
      wsum2(uu[0]*uu[0]+uu[1]*uu[1]+uu[2]*uu[2]+uu[3]*uu[3],
            hs[0]*uu[0]+hs[1]*uu[1]+hs[2]*uu[2]+hs[3]*uu[3], ssuu, dhu);
      madd_body(hs, ssh, h0c, uu, ssuu, dhu, K, sqrtK, rsqK);
      ssh = sq4w(hs);                             // EXACT (feedback state)
      h0c = sqrtf(fmaxf(K + ssh, 1e-7f));

      // ---- gh for next step (folded; reuses exact ssh) + publish + store ----
      float cg = logc_(h0c, ssh, sqrtK, rsqK);
#pragma unroll
      for (int e = 0; e < 4; ++e) gh[e] = cg * hs[e];
      uint2 p; p.x = pkh(gh[0], gh[1]); p.y = pkh(gh[2], gh[3]);
      ((uint2*)lds_gp)[lane] = p;

      float* orow = out + (size_t)(t * B_ + b) * H1_;
      if (lane == 0) orow[0] = h0c;
#pragma unroll
      for (int e = 0; e < 4; ++e) orow[1 + 4 * lane + e] = hs[e];
    }

    // rotate prefetched slices
    xvr_c = xvr_n; xvh_c = xvh_n; xvz_c = xvz_n;
    s0c = s0n; s1c = s1n; s2c = s2n;
  }

  if (wave == 0) {
    float4 hv = {hs[0], hs[1], hs[2], hs[3]};
    ((float4*)(out + (size_t)T_ * B_ * H1_ + (size_t)b * 256))[lane] = hv;
  }
}

// ---------------- launch ----------------
extern "C" void kernel_launch(void* const* d_in, const int* in_sizes, int n_in,
                              void* d_out, int out_size, void* d_ws, size_t ws_size,
                              hipStream_t stream) {
  const float* x    = (const float*)d_in[0];
  const float* k    = (const float*)d_in[1];
  const float* wih  = (const float*)d_in[2];
  const float* whh  = (const float*)d_in[3];
  const float* bias = (const float*)d_in[4];
  float* out = (float*)d_out;

  // ws: Pih (24576 uint4, overlaid by xUss) | Phh (24576 uint4) | xU (32768*768 f)
  uint4* Pih = (uint4*)d_ws;
  uint4* Phh = Pih + 24576;
  float* xU  = (float*)(Phh + 24576);
  float* xUss = (float*)Pih;   // Pih dead after precompute_xu

  pack_weights<<<192, 256, 0, stream>>>(wih, whh, Pih, Phh);
  precompute_xu<<<4096, 256, 0, stream>>>(x, Pih, xU);
  xuss_kernel<<<8192, 256, 0, stream>>>(xU, xUss);
  mobius_gru_scan<<<B_, 512, 0, stream>>>(xU, xUss, Phh, bias, k, out);
}